// Round 4
// baseline (269.145 us; speedup 1.0000x reference)
//
#include <hip/hip_runtime.h>

// TV-gradient divergence, register row-walk v2: no LDS, no barriers, NO SHUFFLES.
// d = ddH(u0) + ddW(u1), u = grad(x)/sqrt(1+|grad(x)|^2), jnp.gradient semantics.
// One-sided boundary diffs == central diffs vs linearly-extrapolated ghosts
// (ghost x for the inner gradient, ghost u0 rows / u1 cols for the outer one).
//
// Each wave owns a 256-col strip, walks NR=16 rows. Per lane per row: float4 at
// j0 + float2 at j0-2 + float2 at j0+4 (overlap loads = L1 hits on neighbors'
// lines). Column-neighbor u1 values are recomputed per-lane (2 extra rsqrt)
// instead of shuffled -> no LDS-pipe latency in the dependency chain.
// Depth-2 load pipeline: row i+4 issued at top of iter i, row i+3 consumed at
// the end of iter i. 8192 waves (2048 blocks) for 8 blocks/CU.

constexpr int H = 1024, W = 1024;
constexpr int NR = 16;
constexpr int NCH = H / NR;     // 64 row chunks

struct Row { float4 q; float2 e, f; };   // q: cols j0..j0+3, e: j0-2,j0-1, f: j0+4,j0+5

__device__ __forceinline__ float4 ld4(const float* p){ return *reinterpret_cast<const float4*>(p); }
__device__ __forceinline__ float2 ld2(const float* p){ return *reinterpret_cast<const float2*>(p); }

__device__ __forceinline__ Row issue_row(const float* Xs, int r, int j0, int cl, int cr){
  const float* p = Xs + (size_t)r * W;
  Row o; o.q = ld4(p + j0); o.e = ld2(p + cl); o.f = ld2(p + cr); return o;
}
// image-left/right ghost columns (only the two lanes at the image edge)
__device__ __forceinline__ void fix_row(Row& o, bool LE0, bool RE63){
  if (LE0)  o.e.y = 2.f*o.q.x - o.q.y;    // x(r,-1) = 2x(r,0)-x(r,1)
  if (RE63) o.f.x = 2.f*o.q.w - o.q.z;    // x(r,W)  = 2x(r,W-1)-x(r,W-2)
}
__device__ __forceinline__ Row ghost2(const Row& a, const Row& b){  // 2a - b
  Row o;
  o.q = make_float4(2.f*a.q.x-b.q.x, 2.f*a.q.y-b.q.y, 2.f*a.q.z-b.q.z, 2.f*a.q.w-b.q.w);
  o.e = make_float2(2.f*a.e.x-b.e.x, 2.f*a.e.y-b.e.y);
  o.f = make_float2(2.f*a.f.x-b.f.x, 2.f*a.f.y-b.f.y);
  return o;
}
__device__ __forceinline__ float4 f4g(const float4 a, const float4 b){  // 2a - b
  return make_float4(2.f*a.x-b.x, 2.f*a.y-b.y, 2.f*a.z-b.z, 2.f*a.w-b.w);
}
// u at row r, cols j0..j0+3 from raw rows rm=x(r-1), rc=x(r), rp=x(r+1).
// gx2/gy2 are 2x the true gradient; one rsqrt shared by u0 and u1.
__device__ __forceinline__ void u_mains(const Row& rm, const Row& rc, const Row& rp,
                                        float4& u0, float4& u1){
  float gx[4] = { rp.q.x-rm.q.x, rp.q.y-rm.q.y, rp.q.z-rm.q.z, rp.q.w-rm.q.w };
  float gy[4] = { rc.q.y-rc.e.y, rc.q.z-rc.q.x, rc.q.w-rc.q.y, rc.f.x-rc.q.z };
  float* o0 = &u0.x; float* o1 = &u1.x;
#pragma unroll
  for (int k = 0; k < 4; ++k){
    float t  = fmaf(gx[k], gx[k], gy[k]*gy[k]);
    float hr = 0.5f * rsqrtf(fmaf(0.25f, t, 1.0f));
    o0[k] = gx[k]*hr; o1[k] = gy[k]*hr;
  }
}
__device__ __forceinline__ float u1_edge(float gx2, float gy2){
  float t = fmaf(gx2, gx2, gy2*gy2);
  return 0.5f * gy2 * rsqrtf(fmaf(0.25f, t, 1.0f));
}

__global__ __launch_bounds__(256, 6) void tv_grad_kernel(const float* __restrict__ X,
                                                         float* __restrict__ D){
  const int tid = threadIdx.x, lane = tid & 63, wv = tid >> 6;
  // XCD-chunked swizzle (gridDim.x % 8 == 0): each XCD walks consecutive chunks
  const int b = blockIdx.x, cpx = gridDim.x >> 3;
  const int w = (b & 7) * cpx + (b >> 3);
  const int slice = w / NCH, chunk = w % NCH;
  const int r0 = chunk * NR;
  const int c0 = wv << 8;
  const int j0 = c0 + (lane << 2);
  const bool LE0  = (j0 == 0), RE63 = (j0 == W - 4);
  const int cl = LE0  ? 0     : j0 - 2;
  const int cr = RE63 ? W - 2 : j0 + 4;
  const float* Xs = X + (size_t)slice * (H * W);
  float*       Ds = D + (size_t)slice * (H * W);

  // ---- prologue: rows r0-2 .. r0+2 resident, r0+3 in flight ---------------
  Row A  = issue_row(Xs, max(r0 - 2, 0), j0, cl, cr);
  Row B  = issue_row(Xs, max(r0 - 1, 0), j0, cl, cr);
  Row C  = issue_row(Xs, r0,             j0, cl, cr);
  Row Dr = issue_row(Xs, r0 + 1,         j0, cl, cr);
  Row E  = issue_row(Xs, r0 + 2,         j0, cl, cr);   // r0+2 <= H-14, no clamp
  Row Rf = issue_row(Xs, r0 + 3,         j0, cl, cr);
  fix_row(A, LE0, RE63); fix_row(B, LE0, RE63); fix_row(C, LE0, RE63);
  fix_row(Dr, LE0, RE63); fix_row(E, LE0, RE63);
  if (r0 == 0) B = ghost2(C, Dr);        // ghost row -1 (A stays junk; fixed at i==0)
  float4 u0m, u0c, u1c;
  { float4 zz; u_mains(A, B, C, u0m, zz); }  // u0(r0-1); garbage iff r0==0
  u_mains(B, C, Dr, u0c, u1c);               // u(r0)
  Row Rm = B, Rc = C, Rp = Dr, Rq = E;

  // ---- main walk (full unroll; rows: Rm=i-1, Rc=i, Rp=i+1, Rq=i+2) --------
#pragma unroll
  for (int k = 0; k < NR; ++k){
    const int i = r0 + k;
    Row Rg = issue_row(Xs, min(i + 4, H - 1), j0, cl, cr);   // depth-2 prefetch

    float4 u0p, u1p;
    if (k == NR - 1 && i == H - 1) {       // u0(H) = 2u0(H-1)-u0(H-2) (ghost u)
      u0p = f4g(u0c, u0m);
      u1p = u1c;                           // unused after
    } else {
      u_mains(Rc, Rp, Rq, u0p, u1p);       // u(i+1)
    }
    if (k == 0 && i == 0) u0m = f4g(u0c, u0p);   // u0(-1) = 2u0(0)-u0(1)

    // edge u1 at row i, cols j0-1 and j0+4 (redundant per-lane compute)
    float u1L = u1_edge(Rp.e.y - Rm.e.y, Rc.q.x - Rc.e.x);
    float u1R = u1_edge(Rp.f.x - Rm.f.x, Rc.f.y - Rc.q.w);
    if (LE0)  u1L = 2.f*u1c.x - u1c.y;     // ghost u1(i,-1)
    if (RE63) u1R = 2.f*u1c.w - u1c.z;     // ghost u1(i,W)

    float4 d;
    d.x = 0.5f*((u0p.x - u0m.x) + (u1c.y - u1L));
    d.y = 0.5f*((u0p.y - u0m.y) + (u1c.z - u1c.x));
    d.z = 0.5f*((u0p.z - u0m.z) + (u1c.w - u1c.y));
    d.w = 0.5f*((u0p.w - u0m.w) + (u1R   - u1c.z));
    *reinterpret_cast<float4*>(Ds + (size_t)i * W + j0) = d;

    // roll
    u0m = u0c; u0c = u0p; u1c = u1p;
    Rm = Rc; Rc = Rp; Rp = Rq;
    if (k >= NR - 3 && i + 3 >= H) {
      Rq = ghost2(Rp, Rc);                 // row H = 2x(H-1)-x(H-2); >H: finite junk
    } else {
      fix_row(Rf, LE0, RE63);
      Rq = Rf;
    }
    Rf = Rg;
  }
}

extern "C" void kernel_launch(void* const* d_in, const int* in_sizes, int n_in,
                              void* d_out, int out_size, void* d_ws, size_t ws_size,
                              hipStream_t stream) {
  const float* X = (const float*)d_in[0];
  float* Dout = (float*)d_out;
  const int n_slices = in_sizes[0] / (H * W);          // 32
  dim3 grid(n_slices * NCH, 1, 1);                     // 2048 blocks x 4 waves
  tv_grad_kernel<<<grid, dim3(256, 1, 1), 0, stream>>>(X, Dout);
}